// Round 5
// baseline (352.009 us; speedup 1.0000x reference)
//
// CategoryAttention: softmax over the HEADS axis (faithful bug reproduction).
// Pipeline: 3 projection GEMMs (fp32->bf16 MFMA) -> pass_a (denominator over h)
//           -> pass_b (recompute energy, P*V) -> output GEMM.
// Round-5 changes vs the passing 1350us VALU baseline:
//  - pass_a/pass_b moved onto MFMA with LDS-staged operands (GEMM-verified idiom)
//  - GEMM retiled 128x128 -> 64x128 (512 blocks = 2/CU, was 1/CU at 25% occupancy)
//  - extra __syncthreads in pass_b between P LDS write and fragment read
#include <hip/hip_runtime.h>
#include <hip/hip_bf16.h>
#include <hip/hip_fp16.h>

#define DM 1024
#define NH 16
#define HD 64
#define LL 2048

typedef __attribute__((ext_vector_type(8))) short bf16x8;
typedef __attribute__((ext_vector_type(4))) float f32x4;

#define MFMA16(a,b,c) __builtin_amdgcn_mfma_f32_16x16x32_bf16((a),(b),(c),0,0,0)

__device__ __forceinline__ ushort f2bf(float f) {
  union { float f; unsigned int u; } v; v.f = f;
  unsigned int u = v.u + 0x7fffu + ((v.u >> 16) & 1u);
  return (ushort)(u >> 16);
}
__device__ __forceinline__ float bf2f(ushort h) {
  union { unsigned int u; float f; } v; v.u = ((unsigned int)h) << 16; return v.f;
}

// GEMM: C[m][n] = sum_k A[m][k] * W[n][k] + bias[n]; 64x128 tile, 4 waves.
// MODE 0: A fp32, out bf16 head-split [B][NH][L][HD]
// MODE 1: A fp32, out bf16 transposed  [B][NH][HD][L]
// MODE 2: A bf16, out fp32 plain [m][n]
template<int MODE>
__global__ __launch_bounds__(256) void gemm_k(const float* __restrict__ Af,
                                              const ushort* __restrict__ Ab,
                                              const float* __restrict__ Wf,
                                              const float* __restrict__ bias,
                                              float* __restrict__ outf,
                                              ushort* __restrict__ outb) {
  __shared__ ushort lA[64][40];
  __shared__ ushort lB[128][40];
  const int m0 = blockIdx.x * 64, n0 = blockIdx.y * 128;
  const int t = threadIdx.x;
  const int w = t >> 6, lane = t & 63, lr = lane & 15, lg = lane >> 4;
  const int wm = (w >> 1) * 32, wn = (w & 1) * 64;
  const int srow = t >> 1, shalf = t & 1;

  f32x4 acc[2][4];
  #pragma unroll
  for (int i = 0; i < 2; ++i)
    #pragma unroll
    for (int j = 0; j < 4; ++j) acc[i][j] = (f32x4){0.f, 0.f, 0.f, 0.f};

  for (int k0 = 0; k0 < DM; k0 += 32) {
    __syncthreads();
    if (t < 128) {
      if (MODE == 2) {
        const ushort* s = Ab + (m0 + srow) * DM + k0 + shalf * 16;
        *(bf16x8*)&lA[srow][shalf * 16]     = *(const bf16x8*)s;
        *(bf16x8*)&lA[srow][shalf * 16 + 8] = *(const bf16x8*)(s + 8);
      } else {
        const float* s = Af + (m0 + srow) * DM + k0 + shalf * 16;
        #pragma unroll
        for (int i = 0; i < 4; ++i) {
          float4 v = *(const float4*)(s + i * 4);
          union { ushort u[4]; unsigned long long ll; } o;
          o.u[0] = f2bf(v.x); o.u[1] = f2bf(v.y); o.u[2] = f2bf(v.z); o.u[3] = f2bf(v.w);
          *(unsigned long long*)&lA[srow][shalf * 16 + i * 4] = o.ll;
        }
      }
    }
    {
      const float* s = Wf + (n0 + srow) * DM + k0 + shalf * 16;
      #pragma unroll
      for (int i = 0; i < 4; ++i) {
        float4 v = *(const float4*)(s + i * 4);
        union { ushort u[4]; unsigned long long ll; } o;
        o.u[0] = f2bf(v.x); o.u[1] = f2bf(v.y); o.u[2] = f2bf(v.z); o.u[3] = f2bf(v.w);
        *(unsigned long long*)&lB[srow][shalf * 16 + i * 4] = o.ll;
      }
    }
    __syncthreads();
    bf16x8 aF[2], bF[4];
    #pragma unroll
    for (int i = 0; i < 2; ++i) aF[i] = *(const bf16x8*)&lA[wm + i * 16 + lr][lg * 8];
    #pragma unroll
    for (int j = 0; j < 4; ++j) bF[j] = *(const bf16x8*)&lB[wn + j * 16 + lr][lg * 8];
    #pragma unroll
    for (int i = 0; i < 2; ++i)
      #pragma unroll
      for (int j = 0; j < 4; ++j)
        acc[i][j] = MFMA16(aF[i], bF[j], acc[i][j]);
  }

  #pragma unroll
  for (int i = 0; i < 2; ++i)
    #pragma unroll
    for (int j = 0; j < 4; ++j)
      #pragma unroll
      for (int r = 0; r < 4; ++r) {
        int m = m0 + wm + i * 16 + lg * 4 + r;
        int n = n0 + wn + j * 16 + lr;
        float v = acc[i][j][r] + bias[n];
        if (MODE == 2) {
          outf[m * DM + n] = v;
        } else {
          int b = m >> 11, q = m & 2047, h = n >> 6, d = n & 63;
          if (MODE == 0)
            outb[((b * NH + h) * LL + q) * HD + d] = f2bf(v);
          else
            outb[((b * NH + h) * HD + d) * LL + q] = f2bf(v);
        }
      }
}

// Pass A (MFMA): rdenH[b][q][k] = 1 / sum_h exp(scale*<Qh,Kh>)
// Block: 128q x 128k tile; 4 waves, each 32q x 128k; per head stage Q/K in LDS.
__global__ __launch_bounds__(256) void pass_a_m(const ushort* __restrict__ Qh,
                                                const ushort* __restrict__ Kh,
                                                __half* __restrict__ rdenH) {
  __shared__ ushort lQ[128][72];
  __shared__ ushort lK[128][72];
  const int b = blockIdx.z, q0 = blockIdx.y * 128, k0 = blockIdx.x * 128;
  const int t = threadIdx.x, w = t >> 6, lane = t & 63, lr = lane & 15, lg = lane >> 4;
  const float scale = 0.125f;

  f32x4 acc[2][8];
  #pragma unroll
  for (int i = 0; i < 2; ++i)
    #pragma unroll
    for (int j = 0; j < 8; ++j) acc[i][j] = (f32x4){0.f, 0.f, 0.f, 0.f};

  for (int h = 0; h < NH; ++h) {
    __syncthreads();
    #pragma unroll
    for (int u = 0; u < 4; ++u) {
      int c = u * 256 + t;
      int row = c >> 3, col = (c & 7) * 8;
      *(bf16x8*)&lQ[row][col] = *(const bf16x8*)&Qh[((b * NH + h) * LL + q0 + row) * HD + col];
      *(bf16x8*)&lK[row][col] = *(const bf16x8*)&Kh[((b * NH + h) * LL + k0 + row) * HD + col];
    }
    __syncthreads();
    #pragma unroll
    for (int i = 0; i < 2; ++i) {
      bf16x8 a0 = *(const bf16x8*)&lQ[w * 32 + i * 16 + lr][lg * 8];
      bf16x8 a1 = *(const bf16x8*)&lQ[w * 32 + i * 16 + lr][32 + lg * 8];
      #pragma unroll
      for (int j = 0; j < 8; ++j) {
        bf16x8 b0 = *(const bf16x8*)&lK[j * 16 + lr][lg * 8];
        bf16x8 b1 = *(const bf16x8*)&lK[j * 16 + lr][32 + lg * 8];
        f32x4 e = {0.f, 0.f, 0.f, 0.f};
        e = MFMA16(a0, b0, e);
        e = MFMA16(a1, b1, e);
        #pragma unroll
        for (int r = 0; r < 4; ++r) acc[i][j][r] += __expf(e[r] * scale);
      }
    }
  }

  #pragma unroll
  for (int i = 0; i < 2; ++i)
    #pragma unroll
    for (int j = 0; j < 8; ++j)
      #pragma unroll
      for (int r = 0; r < 4; ++r) {
        int q = q0 + w * 32 + i * 16 + lg * 4 + r;
        int k = k0 + j * 16 + lr;
        rdenH[(b * LL + q) * LL + k] = __float2half(1.0f / acc[i][j][r]);
      }
}

// Pass B (MFMA): AO[b][q][h*64+d] = sum_k exp(scale*e)*rden * V[k][d]
// Block: (b, h, 64q); 4 waves, wave w owns q rows w*16..w*16+15; k-tiles of 64.
__global__ __launch_bounds__(256) void pass_b_m(const ushort* __restrict__ Qh,
                                                const ushort* __restrict__ Kh,
                                                const ushort* __restrict__ Vt,
                                                const __half* __restrict__ rdenH,
                                                ushort* __restrict__ AO) {
  __shared__ ushort lQ[64][72];
  __shared__ ushort lK[64][72];
  __shared__ ushort lV[64][72];
  __shared__ ushort lP[4][16][72];
  const int q0 = blockIdx.x * 64, h = blockIdx.y, b = blockIdx.z;
  const int t = threadIdx.x, w = t >> 6, lane = t & 63, lr = lane & 15, lg = lane >> 4;
  const float scale = 0.125f;

  #pragma unroll
  for (int u = 0; u < 2; ++u) {
    int c = u * 256 + t;
    int row = c >> 3, col = (c & 7) * 8;
    *(bf16x8*)&lQ[row][col] = *(const bf16x8*)&Qh[((b * NH + h) * LL + q0 + row) * HD + col];
  }
  __syncthreads();
  bf16x8 aQ0 = *(const bf16x8*)&lQ[w * 16 + lr][lg * 8];
  bf16x8 aQ1 = *(const bf16x8*)&lQ[w * 16 + lr][32 + lg * 8];

  f32x4 accO[4];
  #pragma unroll
  for (int j = 0; j < 4; ++j) accO[j] = (f32x4){0.f, 0.f, 0.f, 0.f};

  for (int k0 = 0; k0 < LL; k0 += 64) {
    __syncthreads();
    #pragma unroll
    for (int u = 0; u < 2; ++u) {
      int c = u * 256 + t;
      int row = c >> 3, col = (c & 7) * 8;
      *(bf16x8*)&lK[row][col] = *(const bf16x8*)&Kh[((b * NH + h) * LL + k0 + row) * HD + col];
      *(bf16x8*)&lV[row][col] = *(const bf16x8*)&Vt[((b * NH + h) * HD + row) * LL + k0 + col];
    }
    __syncthreads();

    // phase 1: e = Q K^T for this wave's 16q x 64k
    f32x4 e[4];
    #pragma unroll
    for (int j = 0; j < 4; ++j) {
      bf16x8 b0 = *(const bf16x8*)&lK[j * 16 + lr][lg * 8];
      bf16x8 b1 = *(const bf16x8*)&lK[j * 16 + lr][32 + lg * 8];
      e[j] = (f32x4){0.f, 0.f, 0.f, 0.f};
      e[j] = MFMA16(aQ0, b0, e[j]);
      e[j] = MFMA16(aQ1, b1, e[j]);
    }
    // phase 2: p = exp(e*scale)*rden -> bf16 via per-wave LDS tile
    #pragma unroll
    for (int j = 0; j < 4; ++j)
      #pragma unroll
      for (int r = 0; r < 4; ++r) {
        int q = q0 + w * 16 + lg * 4 + r;
        int k = k0 + j * 16 + lr;
        float rd = __half2float(rdenH[(b * LL + q) * LL + k]);
        lP[w][lg * 4 + r][j * 16 + lr] = f2bf(__expf(e[j][r] * scale) * rd);
      }
    __syncthreads();  // ensure P writes visible before cross-lane fragment read
    // phase 3: O += P * Vt
    bf16x8 aP0 = *(const bf16x8*)&lP[w][lr][lg * 8];
    bf16x8 aP1 = *(const bf16x8*)&lP[w][lr][32 + lg * 8];
    #pragma unroll
    for (int j = 0; j < 4; ++j) {
      bf16x8 b0 = *(const bf16x8*)&lV[j * 16 + lr][lg * 8];
      bf16x8 b1 = *(const bf16x8*)&lV[j * 16 + lr][32 + lg * 8];
      accO[j] = MFMA16(aP0, b0, accO[j]);
      accO[j] = MFMA16(aP1, b1, accO[j]);
    }
  }

  #pragma unroll
  for (int j = 0; j < 4; ++j)
    #pragma unroll
    for (int r = 0; r < 4; ++r) {
      int q = q0 + w * 16 + lg * 4 + r;
      int d = j * 16 + lr;
      AO[(b * LL + q) * DM + h * HD + d] = f2bf(accO[j][r]);
    }
}

extern "C" void kernel_launch(void* const* d_in, const int* in_sizes, int n_in,
                              void* d_out, int out_size, void* d_ws, size_t ws_size,
                              hipStream_t stream) {
  const float* query = (const float*)d_in[0];
  const float* key   = (const float*)d_in[1];
  const float* value = (const float*)d_in[2];
  const float* Wq_w  = (const float*)d_in[3];
  const float* Wq_b  = (const float*)d_in[4];
  const float* Wk_w  = (const float*)d_in[5];
  const float* Wk_b  = (const float*)d_in[6];
  const float* Wv_w  = (const float*)d_in[7];
  const float* Wv_b  = (const float*)d_in[8];
  const float* Wo_w  = (const float*)d_in[9];
  const float* Wo_b  = (const float*)d_in[10];

  char* ws = (char*)d_ws;
  ushort* Qh  = (ushort*)(ws);                 // 8 MB
  ushort* Kh  = (ushort*)(ws + (8u  << 20));   // 8 MB
  ushort* Vt  = (ushort*)(ws + (16u << 20));   // 8 MB
  ushort* AO  = (ushort*)(ws + (24u << 20));   // 8 MB
  __half* rdn = (__half*)(ws + (32u << 20));   // 16 MB -> total 48 MB

  dim3 ggrid(64, 8);
  gemm_k<0><<<ggrid, 256, 0, stream>>>(query, nullptr, Wq_w, Wq_b, nullptr, Qh);
  gemm_k<0><<<ggrid, 256, 0, stream>>>(key,   nullptr, Wk_w, Wk_b, nullptr, Kh);
  gemm_k<1><<<ggrid, 256, 0, stream>>>(value, nullptr, Wv_w, Wv_b, nullptr, Vt);

  pass_a_m<<<dim3(16, 16, 2), 256, 0, stream>>>(Qh, Kh, rdn);
  pass_b_m<<<dim3(32, NH, 2), 256, 0, stream>>>(Qh, Kh, Vt, rdn, AO);

  gemm_k<2><<<ggrid, 256, 0, stream>>>(nullptr, AO, Wo_w, Wo_b, (float*)d_out, nullptr);
}

// Round 6
// 273.417 us; speedup vs baseline: 1.2874x; 1.2874x over previous
//
// CategoryAttention (softmax over HEADS axis). Round 6.
// vs round 5 (352us): (1) pre-convert A/W to bf16 -> all-bf16 GEMM staging;
// (2) pass_b 128q/block (2x MFMA density), middle barrier dropped (lP wave-private);
// (3) rden stored in d_out (dead before final GEMM); ws footprint stays 48 MB.
#include <hip/hip_runtime.h>
#include <hip/hip_bf16.h>
#include <hip/hip_fp16.h>

#define DM 1024
#define NH 16
#define HD 64
#define LL 2048

typedef __attribute__((ext_vector_type(8))) short bf16x8;
typedef __attribute__((ext_vector_type(4))) float f32x4;

#define MFMA16(a,b,c) __builtin_amdgcn_mfma_f32_16x16x32_bf16((a),(b),(c),0,0,0)

__device__ __forceinline__ ushort f2bf(float f) {
  union { float f; unsigned int u; } v; v.f = f;
  unsigned int u = v.u + 0x7fffu + ((v.u >> 16) & 1u);
  return (ushort)(u >> 16);
}

// ---- batched fp32 -> bf16 convert over up to 5 regions ----
__global__ __launch_bounds__(256) void cvt5(const float* __restrict__ s0, ushort* __restrict__ d0, int n0,
                                            const float* __restrict__ s1, ushort* __restrict__ d1, int n1,
                                            const float* __restrict__ s2, ushort* __restrict__ d2, int n2,
                                            const float* __restrict__ s3, ushort* __restrict__ d3, int n3,
                                            const float* __restrict__ s4, ushort* __restrict__ d4, int n4) {
  int i = (blockIdx.x * 256 + threadIdx.x) * 4;
  const float* s; ushort* d;
  if (i < n0) { s = s0; d = d0; }
  else if ((i -= n0) < n1) { s = s1; d = d1; }
  else if ((i -= n1) < n2) { s = s2; d = d2; }
  else if ((i -= n2) < n3) { s = s3; d = d3; }
  else if ((i -= n3) < n4) { s = s4; d = d4; }
  else return;
  float4 v = *(const float4*)(s + i);
  union { ushort u[4]; unsigned long long ll; } o;
  o.u[0] = f2bf(v.x); o.u[1] = f2bf(v.y); o.u[2] = f2bf(v.z); o.u[3] = f2bf(v.w);
  *(unsigned long long*)(d + i) = o.ll;
}

// ---- GEMM (all-bf16 inputs): C[m][n] = sum_k A[m][k]*W[n][k] + bias[n]; 64x128 tile ----
// MODE 0: out bf16 head-split [B][NH][L][HD]; MODE 1: out bf16 [B][NH][HD][L]; MODE 2: out fp32 [m][n]
template<int MODE>
__global__ __launch_bounds__(256) void gemm_b(const ushort* __restrict__ Ab,
                                              const ushort* __restrict__ Wb,
                                              const float* __restrict__ bias,
                                              float* __restrict__ outf,
                                              ushort* __restrict__ outb) {
  __shared__ ushort lA[64][40];
  __shared__ ushort lB[128][40];
  const int m0 = blockIdx.x * 64, n0 = blockIdx.y * 128;
  const int t = threadIdx.x;
  const int w = t >> 6, lane = t & 63, lr = lane & 15, lg = lane >> 4;
  const int wm = (w >> 1) * 32, wn = (w & 1) * 64;
  const int srow = t >> 1, shalf = t & 1;

  f32x4 acc[2][4];
  #pragma unroll
  for (int i = 0; i < 2; ++i)
    #pragma unroll
    for (int j = 0; j < 4; ++j) acc[i][j] = (f32x4){0.f, 0.f, 0.f, 0.f};

  for (int k0 = 0; k0 < DM; k0 += 32) {
    __syncthreads();
    if (t < 128) {
      const ushort* s = Ab + (m0 + srow) * DM + k0 + shalf * 16;
      *(bf16x8*)&lA[srow][shalf * 16]     = *(const bf16x8*)s;
      *(bf16x8*)&lA[srow][shalf * 16 + 8] = *(const bf16x8*)(s + 8);
    }
    {
      const ushort* s = Wb + (n0 + srow) * DM + k0 + shalf * 16;
      *(bf16x8*)&lB[srow][shalf * 16]     = *(const bf16x8*)s;
      *(bf16x8*)&lB[srow][shalf * 16 + 8] = *(const bf16x8*)(s + 8);
    }
    __syncthreads();
    bf16x8 aF[2], bF[4];
    #pragma unroll
    for (int i = 0; i < 2; ++i) aF[i] = *(const bf16x8*)&lA[wm + i * 16 + lr][lg * 8];
    #pragma unroll
    for (int j = 0; j < 4; ++j) bF[j] = *(const bf16x8*)&lB[wn + j * 16 + lr][lg * 8];
    #pragma unroll
    for (int i = 0; i < 2; ++i)
      #pragma unroll
      for (int j = 0; j < 4; ++j)
        acc[i][j] = MFMA16(aF[i], bF[j], acc[i][j]);
  }

  #pragma unroll
  for (int i = 0; i < 2; ++i)
    #pragma unroll
    for (int j = 0; j < 4; ++j)
      #pragma unroll
      for (int r = 0; r < 4; ++r) {
        int m = m0 + wm + i * 16 + lg * 4 + r;
        int n = n0 + wn + j * 16 + lr;
        float v = acc[i][j][r] + bias[n];
        if (MODE == 2) {
          outf[m * DM + n] = v;
        } else {
          int b = m >> 11, q = m & 2047, h = n >> 6, d = n & 63;
          if (MODE == 0)
            outb[((b * NH + h) * LL + q) * HD + d] = f2bf(v);
          else
            outb[((b * NH + h) * HD + d) * LL + q] = f2bf(v);
        }
      }
}

// ---- Pass A (MFMA): rdenH[b][q][k] = 1 / sum_h exp(scale*<Qh,Kh>); 128x128 tile ----
__global__ __launch_bounds__(256) void pass_a_m(const ushort* __restrict__ Qh,
                                                const ushort* __restrict__ Kh,
                                                __half* __restrict__ rdenH) {
  __shared__ ushort lQ[128][72];
  __shared__ ushort lK[128][72];
  const int b = blockIdx.z, q0 = blockIdx.y * 128, k0 = blockIdx.x * 128;
  const int t = threadIdx.x, w = t >> 6, lane = t & 63, lr = lane & 15, lg = lane >> 4;
  const float scale = 0.125f;

  f32x4 acc[2][8];
  #pragma unroll
  for (int i = 0; i < 2; ++i)
    #pragma unroll
    for (int j = 0; j < 8; ++j) acc[i][j] = (f32x4){0.f, 0.f, 0.f, 0.f};

  for (int h = 0; h < NH; ++h) {
    __syncthreads();
    #pragma unroll
    for (int u = 0; u < 4; ++u) {
      int c = u * 256 + t;
      int row = c >> 3, col = (c & 7) * 8;
      *(bf16x8*)&lQ[row][col] = *(const bf16x8*)&Qh[((b * NH + h) * LL + q0 + row) * HD + col];
      *(bf16x8*)&lK[row][col] = *(const bf16x8*)&Kh[((b * NH + h) * LL + k0 + row) * HD + col];
    }
    __syncthreads();
    #pragma unroll
    for (int i = 0; i < 2; ++i) {
      bf16x8 a0 = *(const bf16x8*)&lQ[w * 32 + i * 16 + lr][lg * 8];
      bf16x8 a1 = *(const bf16x8*)&lQ[w * 32 + i * 16 + lr][32 + lg * 8];
      #pragma unroll
      for (int j = 0; j < 8; ++j) {
        bf16x8 b0 = *(const bf16x8*)&lK[j * 16 + lr][lg * 8];
        bf16x8 b1 = *(const bf16x8*)&lK[j * 16 + lr][32 + lg * 8];
        f32x4 e = {0.f, 0.f, 0.f, 0.f};
        e = MFMA16(a0, b0, e);
        e = MFMA16(a1, b1, e);
        #pragma unroll
        for (int r = 0; r < 4; ++r) acc[i][j][r] += __expf(e[r] * scale);
      }
    }
  }

  #pragma unroll
  for (int i = 0; i < 2; ++i)
    #pragma unroll
    for (int j = 0; j < 8; ++j)
      #pragma unroll
      for (int r = 0; r < 4; ++r) {
        int q = q0 + w * 32 + i * 16 + lg * 4 + r;
        int k = k0 + j * 16 + lr;
        rdenH[(b * LL + q) * LL + k] = __float2half(1.0f / acc[i][j][r]);
      }
}

// ---- Pass B (MFMA): AO[b][q][h*64+d] = sum_k exp(scale*e)*rden * V[k][d] ----
// Block: (b, h, 128q); 4 waves, wave w owns q rows [w*32, w*32+32); k-tiles of 64.
__global__ __launch_bounds__(256) void pass_b_m(const ushort* __restrict__ Qh,
                                                const ushort* __restrict__ Kh,
                                                const ushort* __restrict__ Vt,
                                                const __half* __restrict__ rdenH,
                                                ushort* __restrict__ AO) {
  __shared__ ushort lQ[128][72];
  __shared__ ushort lK[64][72];
  __shared__ ushort lV[64][72];
  __shared__ ushort lP[4][32][72];
  const int q0 = blockIdx.x * 128, h = blockIdx.y, b = blockIdx.z;
  const int t = threadIdx.x, w = t >> 6, lane = t & 63, lr = lane & 15, lg = lane >> 4;
  const float scale = 0.125f;

  #pragma unroll
  for (int u = 0; u < 4; ++u) {
    int c = u * 256 + t;
    int row = c >> 3, col = (c & 7) * 8;
    *(bf16x8*)&lQ[row][col] = *(const bf16x8*)&Qh[((b * NH + h) * LL + q0 + row) * HD + col];
  }
  __syncthreads();
  bf16x8 aQ0[2], aQ1[2];
  #pragma unroll
  for (int g = 0; g < 2; ++g) {
    aQ0[g] = *(const bf16x8*)&lQ[w * 32 + g * 16 + lr][lg * 8];
    aQ1[g] = *(const bf16x8*)&lQ[w * 32 + g * 16 + lr][32 + lg * 8];
  }

  f32x4 accO[2][4];
  #pragma unroll
  for (int g = 0; g < 2; ++g)
    #pragma unroll
    for (int j = 0; j < 4; ++j) accO[g][j] = (f32x4){0.f, 0.f, 0.f, 0.f};

  for (int k0 = 0; k0 < LL; k0 += 64) {
    __syncthreads();
    #pragma unroll
    for (int u = 0; u < 2; ++u) {
      int c = u * 256 + t;
      int row = c >> 3, col = (c & 7) * 8;
      *(bf16x8*)&lK[row][col] = *(const bf16x8*)&Kh[((b * NH + h) * LL + k0 + row) * HD + col];
      *(bf16x8*)&lV[row][col] = *(const bf16x8*)&Vt[((b * NH + h) * HD + row) * LL + k0 + col];
    }
    __syncthreads();

    #pragma unroll
    for (int g = 0; g < 2; ++g) {
      // phase 1: e = Q K^T for this group's 16q x 64k
      f32x4 e[4];
      #pragma unroll
      for (int j = 0; j < 4; ++j) {
        bf16x8 b0 = *(const bf16x8*)&lK[j * 16 + lr][lg * 8];
        bf16x8 b1 = *(const bf16x8*)&lK[j * 16 + lr][32 + lg * 8];
        e[j] = (f32x4){0.f, 0.f, 0.f, 0.f};
        e[j] = MFMA16(aQ0[g], b0, e[j]);
        e[j] = MFMA16(aQ1[g], b1, e[j]);
      }
      // phase 2: p = exp(e*scale)*rden -> bf16 via wave-private LDS tile
      #pragma unroll
      for (int j = 0; j < 4; ++j)
        #pragma unroll
        for (int r = 0; r < 4; ++r) {
          int q = q0 + w * 32 + g * 16 + lg * 4 + r;
          int k = k0 + j * 16 + lr;
          float rd = __half2float(rdenH[(b * LL + q) * LL + k]);
          lP[w][g * 16 + lg * 4 + r][j * 16 + lr] = f2bf(__expf(e[j][r] * scale) * rd);
        }
    }
    // phase 3: O += P * Vt  (wave-private lP; same-array dep ordered by compiler)
    #pragma unroll
    for (int g = 0; g < 2; ++g) {
      bf16x8 aP0 = *(const bf16x8*)&lP[w][g * 16 + lr][lg * 8];
      bf16x8 aP1 = *(const bf16x8*)&lP[w][g * 16 + lr][32 + lg * 8];
      #pragma unroll
      for (int j = 0; j < 4; ++j) {
        bf16x8 b0 = *(const bf16x8*)&lV[j * 16 + lr][lg * 8];
        bf16x8 b1 = *(const bf16x8*)&lV[j * 16 + lr][32 + lg * 8];
        accO[g][j] = MFMA16(aP0, b0, accO[g][j]);
        accO[g][j] = MFMA16(aP1, b1, accO[g][j]);
      }
    }
  }

  #pragma unroll
  for (int g = 0; g < 2; ++g)
    #pragma unroll
    for (int j = 0; j < 4; ++j)
      #pragma unroll
      for (int r = 0; r < 4; ++r) {
        int q = q0 + w * 32 + g * 16 + lg * 4 + r;
        int d = j * 16 + lr;
        AO[(b * LL + q) * DM + h * HD + d] = f2bf(accO[g][j][r]);
      }
}

extern "C" void kernel_launch(void* const* d_in, const int* in_sizes, int n_in,
                              void* d_out, int out_size, void* d_ws, size_t ws_size,
                              hipStream_t stream) {
  const float* query = (const float*)d_in[0];
  const float* key   = (const float*)d_in[1];
  const float* value = (const float*)d_in[2];
  const float* Wq_w  = (const float*)d_in[3];
  const float* Wq_b  = (const float*)d_in[4];
  const float* Wk_w  = (const float*)d_in[5];
  const float* Wk_b  = (const float*)d_in[6];
  const float* Wv_w  = (const float*)d_in[7];
  const float* Wv_b  = (const float*)d_in[8];
  const float* Wo_w  = (const float*)d_in[9];
  const float* Wo_b  = (const float*)d_in[10];

  char* ws = (char*)d_ws;
  ushort* Qh  = (ushort*)(ws);                 // [0,8) MB
  ushort* Kh  = (ushort*)(ws + (8u  << 20));   // [8,16)
  ushort* Vt  = (ushort*)(ws + (16u << 20));   // [16,24)
  ushort* AO  = (ushort*)(ws + (24u << 20));   // [24,32) written by pass_b (late)
  ushort* Wqb = (ushort*)(ws + (24u << 20));   // [24,26) early, dead before AO
  ushort* Wkb = (ushort*)(ws + (26u << 20));   // [26,28)
  ushort* Wvb = (ushort*)(ws + (28u << 20));   // [28,30)
  ushort* qbf = (ushort*)(ws + (32u << 20));   // [32,40) early
  ushort* kbf = (ushort*)(ws + (40u << 20));   // [40,48) early
  ushort* vbf = (ushort*)(ws + (32u << 20));   // [32,40) reused after gemmQ
  ushort* Wob = (ushort*)(ws + (40u << 20));   // [40,42) after gemmK
  __half* rdn = (__half*)d_out;                // 16 MB exactly; dead before final GEMM

  const int NA = 2 * LL * DM;   // 4194304
  const int NW = DM * DM;       // 1048576

  // batch 1: query, key, Wq, Wk, Wv
  cvt5<<<(2 * NA + 3 * NW) / 1024, 256, 0, stream>>>(
      query, qbf, NA, key, kbf, NA, Wq_w, Wqb, NW, Wk_w, Wkb, NW, Wv_w, Wvb, NW);

  dim3 ggrid(64, 8);
  gemm_b<0><<<ggrid, 256, 0, stream>>>(qbf, Wqb, Wq_b, nullptr, Qh);
  gemm_b<0><<<ggrid, 256, 0, stream>>>(kbf, Wkb, Wk_b, nullptr, Kh);

  // batch 2: value (into qbf region), Wo (into kbf region)
  cvt5<<<(NA + NW) / 1024, 256, 0, stream>>>(
      value, vbf, NA, Wo_w, Wob, NW, nullptr, nullptr, 0, nullptr, nullptr, 0, nullptr, nullptr, 0);

  gemm_b<1><<<ggrid, 256, 0, stream>>>(vbf, Wvb, Wv_b, nullptr, Vt);

  pass_a_m<<<dim3(16, 16, 2), 256, 0, stream>>>(Qh, Kh, rdn);
  pass_b_m<<<dim3(16, NH, 2), 256, 0, stream>>>(Qh, Kh, Vt, rdn, AO);

  gemm_b<2><<<ggrid, 256, 0, stream>>>(AO, Wob, Wo_b, (float*)d_out, nullptr);
}

// Round 7
// 256.107 us; speedup vs baseline: 1.3745x; 1.0676x over previous
//
// CategoryAttention (softmax over HEADS axis). Round 7.
// vs round 6 (273us): GEMM + pass_b K/V staging moved to global_load_lds dwordx4
// with XOR-swizzled per-lane SOURCE (linear LDS dest, swizzled ds_read: rule #21),
// double-buffered 2-phase loop (prefetch next tile before compute, 1 barrier/iter).
// pass_b: lQ/lP union; exp2 fold. pass_a / cvt unchanged (proven).
#include <hip/hip_runtime.h>
#include <hip/hip_bf16.h>
#include <hip/hip_fp16.h>

#define DM 1024
#define NH 16
#define HD 64
#define LL 2048

typedef __attribute__((ext_vector_type(8))) short bf16x8;
typedef __attribute__((ext_vector_type(4))) float f32x4;

#define MFMA16(a,b,c) __builtin_amdgcn_mfma_f32_16x16x32_bf16((a),(b),(c),0,0,0)

// async global->LDS, 16B per lane; dst must be wave-uniform, src per-lane.
#define GL16(g, l) __builtin_amdgcn_global_load_lds( \
    (const __attribute__((address_space(1))) unsigned int*)(g), \
    (__attribute__((address_space(3))) unsigned int*)(l), 16, 0, 0)

__device__ __forceinline__ ushort f2bf(float f) {
  union { float f; unsigned int u; } v; v.f = f;
  unsigned int u = v.u + 0x7fffu + ((v.u >> 16) & 1u);
  return (ushort)(u >> 16);
}

// ---- batched fp32 -> bf16 convert over up to 5 regions ----
__global__ __launch_bounds__(256) void cvt5(const float* __restrict__ s0, ushort* __restrict__ d0, int n0,
                                            const float* __restrict__ s1, ushort* __restrict__ d1, int n1,
                                            const float* __restrict__ s2, ushort* __restrict__ d2, int n2,
                                            const float* __restrict__ s3, ushort* __restrict__ d3, int n3,
                                            const float* __restrict__ s4, ushort* __restrict__ d4, int n4) {
  int i = (blockIdx.x * 256 + threadIdx.x) * 4;
  const float* s; ushort* d;
  if (i < n0) { s = s0; d = d0; }
  else if ((i -= n0) < n1) { s = s1; d = d1; }
  else if ((i -= n1) < n2) { s = s2; d = d2; }
  else if ((i -= n2) < n3) { s = s3; d = d3; }
  else if ((i -= n3) < n4) { s = s4; d = d4; }
  else return;
  float4 v = *(const float4*)(s + i);
  union { ushort u[4]; unsigned long long ll; } o;
  o.u[0] = f2bf(v.x); o.u[1] = f2bf(v.y); o.u[2] = f2bf(v.z); o.u[3] = f2bf(v.w);
  *(unsigned long long*)(d + i) = o.ll;
}

// ---- GEMM: C[m][n] = sum_k A[m][k]*W[n][k] + bias[n] ----
// BM=64 BN=128 BK=64; 4 waves (2m x 2n), each 32x64; global_load_lds staging,
// XOR chunk-swizzle (chunk ^= row&7), double-buffered, 1 barrier/iter.
// MODE 0: out bf16 [B][NH][L][HD]; MODE 1: out bf16 [B][NH][HD][L]; MODE 2: out fp32 [m][n]
template<int MODE>
__global__ __launch_bounds__(256) void gemm_g(const ushort* __restrict__ Ab,
                                              const ushort* __restrict__ Wb,
                                              const float* __restrict__ bias,
                                              float* __restrict__ outf,
                                              ushort* __restrict__ outb) {
  __shared__ ushort lA[2][64][64];
  __shared__ ushort lB[2][128][64];
  const int m0 = blockIdx.x * 64, n0 = blockIdx.y * 128;
  const int t = threadIdx.x;
  const int w = t >> 6, lane = t & 63, lr = lane & 15, lg = lane >> 4;
  const int wm = (w >> 1) * 32, wn = (w & 1) * 64;
  const int lrow8 = lane >> 3;                 // 0..7 within an 8-row chunk group
  const int scol = ((lane & 7) ^ lrow8) * 8;   // swizzled source column (halves)

  f32x4 acc[2][4];
  #pragma unroll
  for (int i = 0; i < 2; ++i)
    #pragma unroll
    for (int j = 0; j < 4; ++j) acc[i][j] = (f32x4){0.f, 0.f, 0.f, 0.f};

  // prologue: stage k0=0 into buf 0
  #pragma unroll
  for (int c = 0; c < 2; ++c) {
    int row = w * 16 + c * 8 + lrow8;
    GL16(Ab + (m0 + row) * DM + scol, &lA[0][w * 16 + c * 8][0]);
  }
  #pragma unroll
  for (int c = 0; c < 4; ++c) {
    int row = w * 32 + c * 8 + lrow8;
    GL16(Wb + (n0 + row) * DM + scol, &lB[0][w * 32 + c * 8][0]);
  }
  __syncthreads();

  int cur = 0;
  for (int k0 = 0; k0 < DM; k0 += 64) {
    if (k0 + 64 < DM) {
      #pragma unroll
      for (int c = 0; c < 2; ++c) {
        int row = w * 16 + c * 8 + lrow8;
        GL16(Ab + (m0 + row) * DM + k0 + 64 + scol, &lA[cur ^ 1][w * 16 + c * 8][0]);
      }
      #pragma unroll
      for (int c = 0; c < 4; ++c) {
        int row = w * 32 + c * 8 + lrow8;
        GL16(Wb + (n0 + row) * DM + k0 + 64 + scol, &lB[cur ^ 1][w * 32 + c * 8][0]);
      }
    }
    #pragma unroll
    for (int ks = 0; ks < 2; ++ks) {
      bf16x8 aF[2], bF[4];
      #pragma unroll
      for (int i = 0; i < 2; ++i) {
        int row = wm + i * 16 + lr;
        aF[i] = *(const bf16x8*)&lA[cur][row][(((ks * 4 + lg) ^ (lr & 7)) * 8)];
      }
      #pragma unroll
      for (int j = 0; j < 4; ++j) {
        int row = wn + j * 16 + lr;
        bF[j] = *(const bf16x8*)&lB[cur][row][(((ks * 4 + lg) ^ (lr & 7)) * 8)];
      }
      #pragma unroll
      for (int i = 0; i < 2; ++i)
        #pragma unroll
        for (int j = 0; j < 4; ++j)
          acc[i][j] = MFMA16(aF[i], bF[j], acc[i][j]);
    }
    __syncthreads();   // reads of cur done; prefetch into cur^1 drained (vmcnt0 at barrier)
    cur ^= 1;
  }

  #pragma unroll
  for (int i = 0; i < 2; ++i)
    #pragma unroll
    for (int j = 0; j < 4; ++j)
      #pragma unroll
      for (int r = 0; r < 4; ++r) {
        int m = m0 + wm + i * 16 + lg * 4 + r;
        int n = n0 + wn + j * 16 + lr;
        float v = acc[i][j][r] + bias[n];
        if (MODE == 2) {
          outf[m * DM + n] = v;
        } else {
          int b = m >> 11, q = m & 2047, h = n >> 6, d = n & 63;
          if (MODE == 0)
            outb[((b * NH + h) * LL + q) * HD + d] = f2bf(v);
          else
            outb[((b * NH + h) * HD + d) * LL + q] = f2bf(v);
        }
      }
}

// ---- Pass A (MFMA): rdenH[b][q][k] = 1 / sum_h exp(scale*<Qh,Kh>); 128x128 tile ----
__global__ __launch_bounds__(256) void pass_a_m(const ushort* __restrict__ Qh,
                                                const ushort* __restrict__ Kh,
                                                __half* __restrict__ rdenH) {
  __shared__ ushort lQ[128][72];
  __shared__ ushort lK[128][72];
  const int b = blockIdx.z, q0 = blockIdx.y * 128, k0 = blockIdx.x * 128;
  const int t = threadIdx.x, w = t >> 6, lane = t & 63, lr = lane & 15, lg = lane >> 4;
  const float scale = 0.125f;

  f32x4 acc[2][8];
  #pragma unroll
  for (int i = 0; i < 2; ++i)
    #pragma unroll
    for (int j = 0; j < 8; ++j) acc[i][j] = (f32x4){0.f, 0.f, 0.f, 0.f};

  for (int h = 0; h < NH; ++h) {
    __syncthreads();
    #pragma unroll
    for (int u = 0; u < 4; ++u) {
      int c = u * 256 + t;
      int row = c >> 3, col = (c & 7) * 8;
      *(bf16x8*)&lQ[row][col] = *(const bf16x8*)&Qh[((b * NH + h) * LL + q0 + row) * HD + col];
      *(bf16x8*)&lK[row][col] = *(const bf16x8*)&Kh[((b * NH + h) * LL + k0 + row) * HD + col];
    }
    __syncthreads();
    #pragma unroll
    for (int i = 0; i < 2; ++i) {
      bf16x8 a0 = *(const bf16x8*)&lQ[w * 32 + i * 16 + lr][lg * 8];
      bf16x8 a1 = *(const bf16x8*)&lQ[w * 32 + i * 16 + lr][32 + lg * 8];
      #pragma unroll
      for (int j = 0; j < 8; ++j) {
        bf16x8 b0 = *(const bf16x8*)&lK[j * 16 + lr][lg * 8];
        bf16x8 b1 = *(const bf16x8*)&lK[j * 16 + lr][32 + lg * 8];
        f32x4 e = {0.f, 0.f, 0.f, 0.f};
        e = MFMA16(a0, b0, e);
        e = MFMA16(a1, b1, e);
        #pragma unroll
        for (int r = 0; r < 4; ++r) acc[i][j][r] += __expf(e[r] * scale);
      }
    }
  }

  #pragma unroll
  for (int i = 0; i < 2; ++i)
    #pragma unroll
    for (int j = 0; j < 8; ++j)
      #pragma unroll
      for (int r = 0; r < 4; ++r) {
        int q = q0 + w * 32 + i * 16 + lg * 4 + r;
        int k = k0 + j * 16 + lr;
        rdenH[(b * LL + q) * LL + k] = __float2half(1.0f / acc[i][j][r]);
      }
}

// ---- Pass B (MFMA): AO[b][q][h*64+d] = sum_k exp(scale*e)*rden * V[k][d] ----
// Block (b,h,128q); 4 waves, wave w owns q in [w*32, w*32+32).
// K/V: global_load_lds + XOR swizzle, double-buffered, prefetch-before-compute.
__global__ __launch_bounds__(256) void pass_b_m(const ushort* __restrict__ Qh,
                                                const ushort* __restrict__ Kh,
                                                const ushort* __restrict__ Vt,
                                                const __half* __restrict__ rdenH,
                                                ushort* __restrict__ AO) {
  __shared__ union UQP { ushort q[128][64]; ushort p[4][32][72]; } U;
  __shared__ ushort lK[2][64][64];
  __shared__ ushort lV[2][64][64];
  const int q0 = blockIdx.x * 128, h = blockIdx.y, b = blockIdx.z;
  const int t = threadIdx.x, w = t >> 6, lane = t & 63, lr = lane & 15, lg = lane >> 4;
  const int lrow8 = lane >> 3;
  const int scol = ((lane & 7) ^ lrow8) * 8;
  const int bh = b * NH + h;
  const float SC_L2E = 0.18033688011112043f;   // 0.125 * log2(e)

  // stage Q (linear layout, read once)
  #pragma unroll
  for (int u = 0; u < 4; ++u) {
    int c = u * 256 + t;
    int row = c >> 3, col = (c & 7) * 8;
    *(bf16x8*)&U.q[row][col] = *(const bf16x8*)&Qh[(bh * LL + q0 + row) * HD + col];
  }
  // prologue K/V stage into buf 0
  #pragma unroll
  for (int c = 0; c < 2; ++c) {
    int row = w * 16 + c * 8 + lrow8;
    GL16(Kh + (bh * LL + row) * HD + scol, &lK[0][w * 16 + c * 8][0]);
    GL16(Vt + (bh * HD + row) * LL + scol, &lV[0][w * 16 + c * 8][0]);
  }
  __syncthreads();

  bf16x8 aQ0[2], aQ1[2];
  #pragma unroll
  for (int g = 0; g < 2; ++g) {
    aQ0[g] = *(const bf16x8*)&U.q[w * 32 + g * 16 + lr][lg * 8];
    aQ1[g] = *(const bf16x8*)&U.q[w * 32 + g * 16 + lr][32 + lg * 8];
  }
  __syncthreads();   // all Q fragment reads complete before any lP (union) write

  f32x4 accO[2][4];
  #pragma unroll
  for (int g = 0; g < 2; ++g)
    #pragma unroll
    for (int j = 0; j < 4; ++j) accO[g][j] = (f32x4){0.f, 0.f, 0.f, 0.f};

  int cur = 0;
  for (int k0 = 0; k0 < LL; k0 += 64) {
    if (k0 + 64 < LL) {
      #pragma unroll
      for (int c = 0; c < 2; ++c) {
        int row = w * 16 + c * 8 + lrow8;
        GL16(Kh + (bh * LL + k0 + 64 + row) * HD + scol, &lK[cur ^ 1][w * 16 + c * 8][0]);
        GL16(Vt + (bh * HD + row) * LL + k0 + 64 + scol, &lV[cur ^ 1][w * 16 + c * 8][0]);
      }
    }
    #pragma unroll
    for (int g = 0; g < 2; ++g) {
      // phase 1: e = Q K^T (16q x 64k)
      f32x4 e[4];
      #pragma unroll
      for (int j = 0; j < 4; ++j) {
        int krow = j * 16 + lr;
        bf16x8 b0 = *(const bf16x8*)&lK[cur][krow][((lg ^ (lr & 7)) * 8)];
        bf16x8 b1 = *(const bf16x8*)&lK[cur][krow][(((4 + lg) ^ (lr & 7)) * 8)];
        e[j] = (f32x4){0.f, 0.f, 0.f, 0.f};
        e[j] = MFMA16(aQ0[g], b0, e[j]);
        e[j] = MFMA16(aQ1[g], b1, e[j]);
      }
      // phase 2: p = exp2(e*scale*log2e)*rden -> bf16 into wave-private union tile
      #pragma unroll
      for (int j = 0; j < 4; ++j)
        #pragma unroll
        for (int r = 0; r < 4; ++r) {
          int q = q0 + w * 32 + g * 16 + lg * 4 + r;
          int k = k0 + j * 16 + lr;
          float rd = __half2float(rdenH[(b * LL + q) * LL + k]);
          U.p[w][g * 16 + lg * 4 + r][j * 16 + lr] = f2bf(exp2f(e[j][r] * SC_L2E) * rd);
        }
    }
    // phase 3: O += P * Vt
    #pragma unroll
    for (int g = 0; g < 2; ++g) {
      bf16x8 aP0 = *(const bf16x8*)&U.p[w][g * 16 + lr][lg * 8];
      bf16x8 aP1 = *(const bf16x8*)&U.p[w][g * 16 + lr][32 + lg * 8];
      #pragma unroll
      for (int j = 0; j < 4; ++j) {
        int vrow = j * 16 + lr;
        bf16x8 b0 = *(const bf16x8*)&lV[cur][vrow][((lg ^ (lr & 7)) * 8)];
        bf16x8 b1 = *(const bf16x8*)&lV[cur][vrow][(((4 + lg) ^ (lr & 7)) * 8)];
        accO[g][j] = MFMA16(aP0, b0, accO[g][j]);
        accO[g][j] = MFMA16(aP1, b1, accO[g][j]);
      }
    }
    __syncthreads();   // reads of buf cur + U.p done; prefetch into cur^1 drained
    cur ^= 1;
  }

  #pragma unroll
  for (int g = 0; g < 2; ++g)
    #pragma unroll
    for (int j = 0; j < 4; ++j)
      #pragma unroll
      for (int r = 0; r < 4; ++r) {
        int q = q0 + w * 32 + g * 16 + lg * 4 + r;
        int d = j * 16 + lr;
        AO[(b * LL + q) * DM + h * HD + d] = f2bf(accO[g][j][r]);
      }
}

extern "C" void kernel_launch(void* const* d_in, const int* in_sizes, int n_in,
                              void* d_out, int out_size, void* d_ws, size_t ws_size,
                              hipStream_t stream) {
  const float* query = (const float*)d_in[0];
  const float* key   = (const float*)d_in[1];
  const float* value = (const float*)d_in[2];
  const float* Wq_w  = (const float*)d_in[3];
  const float* Wq_b  = (const float*)d_in[4];
  const float* Wk_w  = (const float*)d_in[5];
  const float* Wk_b  = (const float*)d_in[6];
  const float* Wv_w  = (const float*)d_in[7];
  const float* Wv_b  = (const float*)d_in[8];
  const float* Wo_w  = (const float*)d_in[9];
  const float* Wo_b  = (const float*)d_in[10];

  char* ws = (char*)d_ws;
  ushort* Qh  = (ushort*)(ws);                 // [0,8) MB
  ushort* Kh  = (ushort*)(ws + (8u  << 20));   // [8,16)
  ushort* Vt  = (ushort*)(ws + (16u << 20));   // [16,24)
  ushort* AO  = (ushort*)(ws + (24u << 20));   // [24,32) written by pass_b (late)
  ushort* Wqb = (ushort*)(ws + (24u << 20));   // [24,26) early, dead before AO
  ushort* Wkb = (ushort*)(ws + (26u << 20));   // [26,28)
  ushort* Wvb = (ushort*)(ws + (28u << 20));   // [28,30)
  ushort* qbf = (ushort*)(ws + (32u << 20));   // [32,40) early
  ushort* kbf = (ushort*)(ws + (40u << 20));   // [40,48) early
  ushort* vbf = (ushort*)(ws + (32u << 20));   // [32,40) reused after gemm Q
  ushort* Wob = (ushort*)(ws + (40u << 20));   // [40,42) after gemm K
  __half* rdn = (__half*)d_out;                // 16 MB exactly; dead before final GEMM

  const int NA = 2 * LL * DM;
  const int NW = DM * DM;

  cvt5<<<(2 * NA + 3 * NW) / 1024, 256, 0, stream>>>(
      query, qbf, NA, key, kbf, NA, Wq_w, Wqb, NW, Wk_w, Wkb, NW, Wv_w, Wvb, NW);

  dim3 ggrid(64, 8);
  gemm_g<0><<<ggrid, 256, 0, stream>>>(qbf, Wqb, Wq_b, nullptr, Qh);
  gemm_g<0><<<ggrid, 256, 0, stream>>>(kbf, Wkb, Wk_b, nullptr, Kh);

  cvt5<<<(NA + NW) / 1024, 256, 0, stream>>>(
      value, vbf, NA, Wo_w, Wob, NW, nullptr, nullptr, 0, nullptr, nullptr, 0, nullptr, nullptr, 0);

  gemm_g<1><<<ggrid, 256, 0, stream>>>(vbf, Wvb, Wv_b, nullptr, Vt);

  pass_a_m<<<dim3(16, 16, 2), 256, 0, stream>>>(Qh, Kh, rdn);
  pass_b_m<<<dim3(16, NH, 2), 256, 0, stream>>>(Qh, Kh, Vt, rdn, AO);

  gemm_g<2><<<ggrid, 256, 0, stream>>>(AO, Wob, Wo_b, (float*)d_out, nullptr);
}